// Round 7
// baseline (655.507 us; speedup 1.0000x reference)
//
#include <hip/hip_runtime.h>

typedef unsigned short u16;
typedef unsigned int   u32;
typedef __attribute__((ext_vector_type(8))) short short8;
typedef __attribute__((ext_vector_type(4))) float f32x4;
typedef __attribute__((ext_vector_type(2))) float f32x2;
typedef __attribute__((ext_vector_type(4))) u32   u32x4;
typedef __attribute__((ext_vector_type(2))) u32   u32x2;

#define MFMA16 __builtin_amdgcn_mfma_f32_16x16x32_bf16

// W pre-split storage: [0,524288) hi of [Wf;Wg]; [524288,1048576) lo; [1048576,1310720) rne(Wh)
__device__ u16 Wsplit[1310720];

__device__ __forceinline__ u16 f2bf(float f) {           // rne
  u32 u = __float_as_uint(f);
  return (u16)((u + 0x7FFFu + ((u >> 16) & 1u)) >> 16);
}
__device__ __forceinline__ u32 cvtpk(float a, float b) { // packed rne {bf16(a),bf16(b)}
  u32 d; asm("v_cvt_pk_bf16_f32 %0, %1, %2" : "=v"(d) : "v"(a), "v"(b)); return d;
}
__device__ __forceinline__ void split2(float a, float b, u32& hi, u32& lo) {
  u32 ua = __float_as_uint(a), ub = __float_as_uint(b);
  hi = __builtin_amdgcn_perm(ub, ua, 0x07060302u);       // {trunc(a), trunc(b)}
  lo = cvtpk(a - __uint_as_float(ua & 0xFFFF0000u), b - __uint_as_float(ub & 0xFFFF0000u));
}
__device__ __forceinline__ void gload16(const void* g, void* l) {
  __builtin_amdgcn_global_load_lds(
      (const __attribute__((address_space(1))) void*)g,
      (__attribute__((address_space(3))) void*)l, 16, 0, 0);
}

// ---------------------------------------------------------------------------
// prep_w: split weights into bf16 hi/lo (runs once per call, trivial cost)
// ---------------------------------------------------------------------------
__global__ __launch_bounds__(256)
void prep_w(const float* __restrict__ Wf, const float* __restrict__ Wg,
            const float* __restrict__ Wh)
{
  const int r = blockIdx.x;                    // 0..1535
  const int k = threadIdx.x * 2;
  const float* src = (r < 512) ? (Wf + (size_t)r * 512)
                   : (r < 1024) ? (Wg + (size_t)(r - 512) * 512)
                                : (Wh + (size_t)(r - 1024) * 512);
  f32x2 v = *(const f32x2*)(src + k);
  if (r < 1024) {
    u32 hi, lo; split2(v[0], v[1], hi, lo);
    *(u32*)(Wsplit + (size_t)r * 512 + k) = hi;
    *(u32*)(Wsplit + 524288 + (size_t)r * 512 + k) = lo;
  } else {
    *(u32*)(Wsplit + 1048576 + (size_t)(r - 1024) * 512 + k) = cvtpk(v[0], v[1]);
  }
}

// ---------------------------------------------------------------------------
// prep_x: x[512][65536] fp32 -> xT[65536][512] bf16 hi(trunc)/lo(rne).
// ---------------------------------------------------------------------------
__global__ __launch_bounds__(256)
void prep_x(const float* __restrict__ x, u16* __restrict__ xhi, u16* __restrict__ xlo)
{
  __shared__ float tile[64 * 256];             // 64 KB, pitch 256 (conflict-free)
  const int bk = blockIdx.x & 7, bn = blockIdx.x >> 3;
  const int t = threadIdx.x;
  const int cw = (t & 63) * 4, r0 = (t >> 6) * 16;
#pragma unroll
  for (int it = 0; it < 16; ++it) {
    const int r = r0 + it;
    *(f32x4*)&tile[r * 256 + cw] =
        *(const f32x4*)(x + (size_t)(bk * 64 + r) * 65536 + (size_t)bn * 256 + cw);
  }
  __syncthreads();
  u32 hi[32], lo[32];
#pragma unroll
  for (int q = 0; q < 32; ++q)
    split2(tile[(2 * q) * 256 + t], tile[(2 * q + 1) * 256 + t], hi[q], lo[q]);
  const size_t ob = (size_t)(bn * 256 + t) * 512 + bk * 64;
#pragma unroll
  for (int c4 = 0; c4 < 8; ++c4) {
    *(u32x4*)(xhi + ob + c4 * 8) = (u32x4){hi[4*c4], hi[4*c4+1], hi[4*c4+2], hi[4*c4+3]};
    *(u32x4*)(xlo + ob + c4 * 8) = (u32x4){lo[4*c4], lo[4*c4+1], lo[4*c4+2], lo[4*c4+3]};
  }
}

// ---------------------------------------------------------------------------
// conv_fg8: EMU bf16-pair GEMM. M=1024 (tm 0,1 = f; 2,3 = g via sigma rows),
// BM=256, BN=128, BK=32, 512 thr = 8 waves (4M x 2N), per-wave 64x64.
// LDS: 3 buffers x 48 KB, linear rows 64 B, source k-slot pre-swizzle (T2).
// Schedule: compiler-scheduled tile interior (plain ds_reads + MFMAs, the
// compiler emits fine-grained lgkmcnt), counted vmcnt(6) (T4, never 0 in
// steady state), ONE barrier per K-tile (protects 3-buffer reuse).
// ---------------------------------------------------------------------------
__global__ __launch_bounds__(512, 2)
void conv_fg8(const u16* __restrict__ xhi, const u16* __restrict__ xlo,
              u16* __restrict__ fhi, u16* __restrict__ flo,
              u16* __restrict__ gThi, u16* __restrict__ gTlo)
{
  __shared__ u16 lds[73728];                    // 144 KB
  const int bid = blockIdx.x;
  const int xcd = bid & 7, idx = bid >> 3;      // 2048 = 8 XCD x (64 tn x 4 tm)
  const int tn = xcd * 64 + (idx >> 2);
  const int tm = idx & 3;
  const bool gmode = tm >= 2;
  const int t = threadIdx.x, lane = t & 63, wid = t >> 6;
  const int wr = wid >> 1, wc = wid & 1;
  const int lr = lane & 15, lq = lane >> 4;

  // staging mapping: row = t>>2 (0..127), swizzled k-slot (involution)
  const int arow = t >> 2;
  const int kslot8 = (((t & 3) ^ ((t >> 3) & 3)) << 3);
  const int garA0 = tm * 256 + arow;
  const int garA1 = garA0 + 128;
  const int bxr = gmode ? ((((tn & 1) << 7) + arow) * 256 + (tn >> 1))
                        : (tn * 128 + arow);
  const int wbyte = wid * 1024;
  char* const L = (char*)lds;

  // fragment read offsets (u16 units), loop-invariant, matching read swizzle
  int offA[4], offB[4];
#pragma unroll
  for (int mi = 0; mi < 4; ++mi) {
    const int rowA = wr * 64 + mi * 16 + lr;
    offA[mi] = rowA * 32 + ((lq ^ ((rowA >> 1) & 3)) << 3);
  }
#pragma unroll
  for (int ni = 0; ni < 4; ++ni) {
    const int rowB = wc * 64 + ni * 16 + lr;
    offB[ni] = 16384 + rowB * 32 + ((lq ^ ((rowB >> 1) & 3)) << 3);
  }

  f32x4 acc[4][4] = {};

  // prologue: stage tiles 0 and 1 (12 gloads/thread), wait first tile's 6
#pragma unroll
  for (int Tp = 0; Tp < 2; ++Tp) {
    const int ko = Tp * 32 + kslot8;
    const int bb = Tp * 49152;
    gload16(Wsplit + (size_t)garA0 * 512 + ko,          L + bb + 0     + wbyte);
    gload16(Wsplit + (size_t)garA1 * 512 + ko,          L + bb + 8192  + wbyte);
    gload16(Wsplit + 524288 + (size_t)garA0 * 512 + ko, L + bb + 16384 + wbyte);
    gload16(Wsplit + 524288 + (size_t)garA1 * 512 + ko, L + bb + 24576 + wbyte);
    gload16(xhi + (size_t)bxr * 512 + ko,               L + bb + 32768 + wbyte);
    gload16(xlo + (size_t)bxr * 512 + ko,               L + bb + 40960 + wbyte);
  }
  asm volatile("s_waitcnt vmcnt(6)" ::: "memory");
  __builtin_amdgcn_s_barrier();
  __builtin_amdgcn_sched_barrier(0);

#pragma unroll 1
  for (int T = 0; T < 16; ++T) {
    const u16* Bp = lds + (T % 3) * 24576;

    // ---- fragment loads (plain; compiler interleaves fine-grained lgkmcnt)
    short8 ah[4], al[4], bh[4], bl[4];
#pragma unroll
    for (int mi = 0; mi < 4; ++mi) {
      ah[mi] = *(const short8*)(Bp + offA[mi]);
      al[mi] = *(const short8*)(Bp + 8192 + offA[mi]);
    }
#pragma unroll
    for (int ni = 0; ni < 4; ++ni) {
      bh[ni] = *(const short8*)(Bp + offB[ni]);
      bl[ni] = *(const short8*)(Bp + 4096 + offB[ni]);
    }
    // ---- prefetch tile T+2 (counted; stays in flight across the barrier)
    if (T < 14) {
      const int bpo = ((T + 2) % 3) * 49152;
      const int ko = (T + 2) * 32 + kslot8;
      gload16(Wsplit + (size_t)garA0 * 512 + ko,          L + bpo + 0     + wbyte);
      gload16(Wsplit + (size_t)garA1 * 512 + ko,          L + bpo + 8192  + wbyte);
      gload16(Wsplit + 524288 + (size_t)garA0 * 512 + ko, L + bpo + 16384 + wbyte);
      gload16(Wsplit + 524288 + (size_t)garA1 * 512 + ko, L + bpo + 24576 + wbyte);
      gload16(xhi + (size_t)bxr * 512 + ko,               L + bpo + 32768 + wbyte);
      gload16(xlo + (size_t)bxr * 512 + ko,               L + bpo + 40960 + wbyte);
    }
    // ---- 48 MFMAs, same-acc chains 16 apart
#pragma unroll
    for (int mi = 0; mi < 4; ++mi)
#pragma unroll
      for (int ni = 0; ni < 4; ++ni)
        acc[mi][ni] = MFMA16(ah[mi], bh[ni], acc[mi][ni], 0, 0, 0);
#pragma unroll
    for (int mi = 0; mi < 4; ++mi)
#pragma unroll
      for (int ni = 0; ni < 4; ++ni)
        acc[mi][ni] = MFMA16(ah[mi], bl[ni], acc[mi][ni], 0, 0, 0);
#pragma unroll
    for (int mi = 0; mi < 4; ++mi)
#pragma unroll
      for (int ni = 0; ni < 4; ++ni)
        acc[mi][ni] = MFMA16(al[mi], bh[ni], acc[mi][ni], 0, 0, 0);
    // ---- tile end: T+1's loads arrived; my reads of buf[T%3] complete;
    // barrier allows iter T+1 to DMA into buf[T%3].
    if (T < 14) { asm volatile("s_waitcnt vmcnt(6)" ::: "memory"); }
    else        { asm volatile("s_waitcnt vmcnt(0)" ::: "memory"); }
    asm volatile("s_waitcnt lgkmcnt(0)" ::: "memory");
    __builtin_amdgcn_s_barrier();
    __builtin_amdgcn_sched_barrier(0);
  }

  // ---- epilogue: per-wave 64x64, hi/lo split write
  const int mbase = tm * 256 + wr * 64;
  const int cbase = tn * 128 + wc * 64;
  u16* dsthi = gmode ? gThi : fhi;
  u16* dstlo = gmode ? gTlo : flo;
  const int chb = gmode ? (mbase - 512) : mbase;
#pragma unroll
  for (int mi = 0; mi < 4; ++mi)
#pragma unroll
    for (int ni = 0; ni < 4; ++ni) {
      const int r0 = chb + mi * 16 + lq * 4;
      const int cc = cbase + ni * 16 + lr;
#pragma unroll
      for (int r = 0; r < 4; ++r) {
        float val = acc[mi][ni][r];
        u32 u = __float_as_uint(val);
        const size_t o = (size_t)(r0 + r) * 65536 + cc;
        dsthi[o] = (u16)(u >> 16);
        dstlo[o] = f2bf(val - __uint_as_float(u & 0xFFFF0000u));
      }
    }
}

// ---------------------------------------------------------------------------
// conv_h: plain bf16 GEMM h = rne(Wh) @ x, all-gload staging, out bf16.
// ---------------------------------------------------------------------------
__global__ __launch_bounds__(256)
void conv_h(const u16* __restrict__ xhi, u16* __restrict__ hb)
{
  __shared__ u16 sA[128 * 32], sB[128 * 32];
  const int bid = blockIdx.x;
  const int xcd = bid & 7, idx = bid >> 3;      // 2048 = 8 x (64 tn x 4 tm)
  const int tn = xcd * 64 + (idx >> 2);
  const int tm = idx & 3;
  const int t = threadIdx.x, lane = t & 63, wid = t >> 6;
  const int wr = wid >> 1, wc = wid & 1, lr = lane & 15, lq = lane >> 4;
  const int grl = t >> 2, gko = t & 3;
  const int ldsb = wid * 1024;

  f32x4 acc[4][4] = {};

  for (int k0 = 0; k0 < 512; k0 += 32) {
#pragma unroll
    for (int q = 0; q < 2; ++q) {
      const int row = q * 64 + grl;
      const size_t ao = (size_t)1048576 + (size_t)(tm * 128 + row) * 512 + k0 + gko * 8;
      gload16(Wsplit + ao, (char*)sA + q * 4096 + ldsb);
      const size_t bo = (size_t)(tn * 128 + row) * 512 + k0 + gko * 8;
      gload16(xhi + bo, (char*)sB + q * 4096 + ldsb);
    }
    __syncthreads();
    short8 af[4], bfr[4];
#pragma unroll
    for (int mi = 0; mi < 4; ++mi)
      af[mi] = *(const short8*)(sA + (wr * 64 + mi * 16 + lr) * 32 + lq * 8);
#pragma unroll
    for (int ni = 0; ni < 4; ++ni)
      bfr[ni] = *(const short8*)(sB + (wc * 64 + ni * 16 + lr) * 32 + lq * 8);
#pragma unroll
    for (int mi = 0; mi < 4; ++mi)
#pragma unroll
      for (int ni = 0; ni < 4; ++ni)
        acc[mi][ni] = MFMA16(af[mi], bfr[ni], acc[mi][ni], 0, 0, 0);
    __syncthreads();
  }
  const int rb = tm * 128 + wr * 64, cbase = tn * 128 + wc * 64;
#pragma unroll
  for (int mi = 0; mi < 4; ++mi)
#pragma unroll
    for (int ni = 0; ni < 4; ++ni) {
      const int r0 = rb + mi * 16 + lq * 4, cc = cbase + ni * 16 + lr;
#pragma unroll
      for (int r = 0; r < 4; ++r)
        hb[(size_t)(r0 + r) * 65536 + cc] = f2bf(acc[mi][ni][r]);
    }
}

// ---------------------------------------------------------------------------
// scores256: one block per channel. S = f[c] @ gT[c]^T (EMU), 256x256 tile,
// full-column softmax -> normalized PT[c][j][i] bf16.
// ---------------------------------------------------------------------------
__global__ __launch_bounds__(512, 2)
void scores256(const u16* __restrict__ fhi, const u16* __restrict__ flo,
               const u16* __restrict__ gThi, const u16* __restrict__ gTlo,
               u16* __restrict__ Pt)
{
  __shared__ u16 sAh[256 * 32], sAl[256 * 32], sBh[256 * 32], sBl[256 * 32]; // 4x16 KB
  float* cmax = (float*)sAh;          // aliases staging (dead after K-loop)
  float* csum = (float*)(sAh + 2048);
  const int c = blockIdx.x;
  const size_t cb = (size_t)c * 65536;
  const int t = threadIdx.x, lane = t & 63, wid = t >> 6;
  const int wr = wid >> 2, wc = wid & 3, lr = lane & 15, lq = lane >> 4;
  const int grl = t >> 2, gko = t & 3;
  const int ldsb = wid * 1024;

  f32x4 acc[8][4] = {};

  for (int k0 = 0; k0 < 256; k0 += 32) {
#pragma unroll
    for (int q = 0; q < 2; ++q) {
      const size_t ao = cb + (size_t)(q * 128 + grl) * 256 + k0 + gko * 8;
      gload16(fhi + ao,  (char*)sAh + q * 8192 + ldsb);
      gload16(flo + ao,  (char*)sAl + q * 8192 + ldsb);
      gload16(gThi + ao, (char*)sBh + q * 8192 + ldsb);
      gload16(gTlo + ao, (char*)sBl + q * 8192 + ldsb);
    }
    __syncthreads();
    short8 bh[4], bl[4];
#pragma unroll
    for (int ni = 0; ni < 4; ++ni) {
      bh[ni] = *(const short8*)(sBh + (wc * 64 + ni * 16 + lr) * 32 + lq * 8);
      bl[ni] = *(const short8*)(sBl + (wc * 64 + ni * 16 + lr) * 32 + lq * 8);
    }
#pragma unroll
    for (int mi = 0; mi < 8; ++mi) {
      short8 ah = *(const short8*)(sAh + (wr * 128 + mi * 16 + lr) * 32 + lq * 8);
      short8 al = *(const short8*)(sAl + (wr * 128 + mi * 16 + lr) * 32 + lq * 8);
#pragma unroll
      for (int ni = 0; ni < 4; ++ni) {
        acc[mi][ni] = MFMA16(ah, bh[ni], acc[mi][ni], 0, 0, 0);
        acc[mi][ni] = MFMA16(ah, bl[ni], acc[mi][ni], 0, 0, 0);
        acc[mi][ni] = MFMA16(al, bh[ni], acc[mi][ni], 0, 0, 0);
      }
    }
    __syncthreads();
  }

#pragma unroll
  for (int ni = 0; ni < 4; ++ni) {
    const int j = wc * 64 + ni * 16 + lr;
    float m = -3.4e38f;
#pragma unroll
    for (int mi = 0; mi < 8; ++mi) {
      f32x4 a = acc[mi][ni];
      m = fmaxf(m, fmaxf(fmaxf(a[0], a[1]), fmaxf(a[2], a[3])));
    }
    m = fmaxf(m, __shfl_xor(m, 16));
    m = fmaxf(m, __shfl_xor(m, 32));
    cmax[wr * 256 + j] = m;
  }
  __syncthreads();
#pragma unroll
  for (int ni = 0; ni < 4; ++ni) {
    const int j = wc * 64 + ni * 16 + lr;
    const float M = fmaxf(cmax[j], cmax[256 + j]);
    float s = 0.f;
#pragma unroll
    for (int mi = 0; mi < 8; ++mi)
#pragma unroll
      for (int r = 0; r < 4; ++r) {
        float e = __expf(acc[mi][ni][r] - M);
        acc[mi][ni][r] = e; s += e;
      }
    s += __shfl_xor(s, 16);
    s += __shfl_xor(s, 32);
    csum[wr * 256 + j] = s;
  }
  __syncthreads();
#pragma unroll
  for (int ni = 0; ni < 4; ++ni) {
    const int j = wc * 64 + ni * 16 + lr;
    const float rs = 1.f / (csum[j] + csum[256 + j]);
#pragma unroll
    for (int mi = 0; mi < 8; ++mi) {
      u32 w0 = cvtpk(acc[mi][ni][0] * rs, acc[mi][ni][1] * rs);
      u32 w1 = cvtpk(acc[mi][ni][2] * rs, acc[mi][ni][3] * rs);
      *(u32x2*)(Pt + cb + (size_t)j * 256 + wr * 128 + mi * 16 + lq * 4) = (u32x2){w0, w1};
    }
  }
}

// ---------------------------------------------------------------------------
// attn: out[c,i,j] = x[c,i,j] + sum_k h[c,i,k] * PT[c,j,k]. Plain bf16.
// ---------------------------------------------------------------------------
__global__ __launch_bounds__(256)
void attn_kernel(const u16* __restrict__ hb, const u16* __restrict__ Pt,
                 const float* __restrict__ x, float* __restrict__ out)
{
  __shared__ u16 sA[128 * 32], sB[128 * 32];
  const int bid = blockIdx.x;
  const int wg = (bid & 7) * 256 + (bid >> 3);
  const int c = wg >> 2, tm = (wg >> 1) & 1, tn = wg & 1;
  const int t = threadIdx.x, lane = t & 63, wid = t >> 6;
  const int wr = wid >> 1, wc = wid & 1, lr = lane & 15, lq = lane >> 4;
  const size_t cb = (size_t)c * 65536;
  const int grl = t >> 2, gko = t & 3;
  const int ldsb = wid * 1024;

  f32x4 acc[4][4] = {};

  for (int k0 = 0; k0 < 256; k0 += 32) {
#pragma unroll
    for (int q = 0; q < 2; ++q) {
      const int row = q * 64 + grl;
      gload16(hb + cb + (size_t)(tm * 128 + row) * 256 + k0 + gko * 8,
              (char*)sA + q * 4096 + ldsb);
      gload16(Pt + cb + (size_t)(tn * 128 + row) * 256 + k0 + gko * 8,
              (char*)sB + q * 4096 + ldsb);
    }
    __syncthreads();
    short8 af[4], bfr[4];
#pragma unroll
    for (int mi = 0; mi < 4; ++mi)
      af[mi] = *(const short8*)(sA + (wr * 64 + mi * 16 + lr) * 32 + lq * 8);
#pragma unroll
    for (int ni = 0; ni < 4; ++ni)
      bfr[ni] = *(const short8*)(sB + (wc * 64 + ni * 16 + lr) * 32 + lq * 8);
#pragma unroll
    for (int mi = 0; mi < 4; ++mi)
#pragma unroll
      for (int ni = 0; ni < 4; ++ni)
        acc[mi][ni] = MFMA16(af[mi], bfr[ni], acc[mi][ni], 0, 0, 0);
    __syncthreads();
  }

  const float* Xc = x + cb;
  float* Oc = out + cb;
  const int rb = tm * 128 + wr * 64, cbase = tn * 128 + wc * 64;
#pragma unroll
  for (int mi = 0; mi < 4; ++mi)
#pragma unroll
    for (int ni = 0; ni < 4; ++ni) {
      const int r0 = rb + mi * 16 + lq * 4, cc = cbase + ni * 16 + lr;
#pragma unroll
      for (int r = 0; r < 4; ++r) {
        const size_t idx = (size_t)(r0 + r) * 256 + cc;
        Oc[idx] = Xc[idx] + acc[mi][ni][r];
      }
    }
}

// ---------------------------------------------------------------------------
extern "C" void kernel_launch(void* const* d_in, const int* in_sizes, int n_in,
                              void* d_out, int out_size, void* d_ws, size_t ws_size,
                              hipStream_t stream)
{
  (void)in_sizes; (void)n_in; (void)out_size; (void)ws_size;
  const float* x  = (const float*)d_in[0];
  const float* Wf = (const float*)d_in[1];
  const float* Wg = (const float*)d_in[2];
  const float* Wh = (const float*)d_in[3];
  float* out = (float*)d_out;
  char*  ws  = (char*)d_ws;

  // ws (256 MiB): [xhi 64][xlo 64][gThi 64][gTlo 64]; d_out hosts f hi/lo.
  u16* xhi  = (u16*)ws;
  u16* xlo  = (u16*)(ws + 67108864);
  u16* gThi = (u16*)(ws + 134217728);
  u16* gTlo = (u16*)(ws + 201326592);
  u16* fhi  = (u16*)d_out;
  u16* flo  = (u16*)d_out + 33554432;
  u16* hb   = xlo;   // h overwrites xlo after conv_fg8
  u16* Pt   = xhi;   // PT overwrites xhi after conv_h

  dim3 blk(256, 1, 1);
  prep_w     <<<dim3(1536, 1, 1), blk, 0, stream>>>(Wf, Wg, Wh);
  prep_x     <<<dim3(2048, 1, 1), blk, 0, stream>>>(x, xhi, xlo);
  conv_fg8   <<<dim3(2048, 1, 1), dim3(512, 1, 1), 0, stream>>>(xhi, xlo, fhi, flo, gThi, gTlo);
  conv_h     <<<dim3(2048, 1, 1), blk, 0, stream>>>(xhi, hb);
  scores256  <<<dim3(512, 1, 1), dim3(512, 1, 1), 0, stream>>>(fhi, flo, gThi, gTlo, Pt);
  attn_kernel<<<dim3(2048, 1, 1), blk, 0, stream>>>(hb, Pt, x, out);
}

// Round 8
// 646.079 us; speedup vs baseline: 1.0146x; 1.0146x over previous
//
#include <hip/hip_runtime.h>

typedef unsigned short u16;
typedef unsigned int   u32;
typedef __attribute__((ext_vector_type(8))) short short8;
typedef __attribute__((ext_vector_type(4))) float f32x4;
typedef __attribute__((ext_vector_type(2))) float f32x2;
typedef __attribute__((ext_vector_type(4))) u32   u32x4;
typedef __attribute__((ext_vector_type(2))) u32   u32x2;

#define MFMA16 __builtin_amdgcn_mfma_f32_16x16x32_bf16

// W pre-split storage: [0,524288) hi of [Wf;Wg]; [524288,1048576) lo; [1048576,1310720) rne(Wh)
__device__ u16 Wsplit[1310720];

__device__ __forceinline__ u16 f2bf(float f) {           // rne
  u32 u = __float_as_uint(f);
  return (u16)((u + 0x7FFFu + ((u >> 16) & 1u)) >> 16);
}
__device__ __forceinline__ u32 cvtpk(float a, float b) { // packed rne {bf16(a),bf16(b)}
  u32 d; asm("v_cvt_pk_bf16_f32 %0, %1, %2" : "=v"(d) : "v"(a), "v"(b)); return d;
}
__device__ __forceinline__ void split2(float a, float b, u32& hi, u32& lo) {
  u32 ua = __float_as_uint(a), ub = __float_as_uint(b);
  hi = __builtin_amdgcn_perm(ub, ua, 0x07060302u);       // {trunc(a), trunc(b)}
  lo = cvtpk(a - __uint_as_float(ua & 0xFFFF0000u), b - __uint_as_float(ub & 0xFFFF0000u));
}
__device__ __forceinline__ void gload16(const void* g, void* l) {
  __builtin_amdgcn_global_load_lds(
      (const __attribute__((address_space(1))) void*)g,
      (__attribute__((address_space(3))) void*)l, 16, 0, 0);
}

// ---------------------------------------------------------------------------
// prep_w: split weights into bf16 hi/lo (runs once per call, trivial cost)
// ---------------------------------------------------------------------------
__global__ __launch_bounds__(256)
void prep_w(const float* __restrict__ Wf, const float* __restrict__ Wg,
            const float* __restrict__ Wh)
{
  const int r = blockIdx.x;                    // 0..1535
  const int k = threadIdx.x * 2;
  const float* src = (r < 512) ? (Wf + (size_t)r * 512)
                   : (r < 1024) ? (Wg + (size_t)(r - 512) * 512)
                                : (Wh + (size_t)(r - 1024) * 512);
  f32x2 v = *(const f32x2*)(src + k);
  if (r < 1024) {
    u32 hi, lo; split2(v[0], v[1], hi, lo);
    *(u32*)(Wsplit + (size_t)r * 512 + k) = hi;
    *(u32*)(Wsplit + 524288 + (size_t)r * 512 + k) = lo;
  } else {
    *(u32*)(Wsplit + 1048576 + (size_t)(r - 1024) * 512 + k) = cvtpk(v[0], v[1]);
  }
}

// ---------------------------------------------------------------------------
// prep_x: x[512][65536] fp32 -> xT[65536][512] bf16 hi(trunc)/lo(rne).
// ---------------------------------------------------------------------------
__global__ __launch_bounds__(256)
void prep_x(const float* __restrict__ x, u16* __restrict__ xhi, u16* __restrict__ xlo)
{
  __shared__ float tile[64 * 256];             // 64 KB, pitch 256 (conflict-free)
  const int bk = blockIdx.x & 7, bn = blockIdx.x >> 3;
  const int t = threadIdx.x;
  const int cw = (t & 63) * 4, r0 = (t >> 6) * 16;
#pragma unroll
  for (int it = 0; it < 16; ++it) {
    const int r = r0 + it;
    *(f32x4*)&tile[r * 256 + cw] =
        *(const f32x4*)(x + (size_t)(bk * 64 + r) * 65536 + (size_t)bn * 256 + cw);
  }
  __syncthreads();
  u32 hi[32], lo[32];
#pragma unroll
  for (int q = 0; q < 32; ++q)
    split2(tile[(2 * q) * 256 + t], tile[(2 * q + 1) * 256 + t], hi[q], lo[q]);
  const size_t ob = (size_t)(bn * 256 + t) * 512 + bk * 64;
#pragma unroll
  for (int c4 = 0; c4 < 8; ++c4) {
    *(u32x4*)(xhi + ob + c4 * 8) = (u32x4){hi[4*c4], hi[4*c4+1], hi[4*c4+2], hi[4*c4+3]};
    *(u32x4*)(xlo + ob + c4 * 8) = (u32x4){lo[4*c4], lo[4*c4+1], lo[4*c4+2], lo[4*c4+3]};
  }
}

// ---------------------------------------------------------------------------
// conv_fg8: EMU bf16-pair GEMM. M=1024 (tm 0,1 = f; 2,3 = g via sigma rows),
// BM=256, BN=128, BK=32, 512 thr = 8 waves (4M x 2N), per-wave 64x64.
// LDS: 3 buffers x 48 KB, linear rows 64 B, source k-slot pre-swizzle (T2).
// Schedule: m201 cadence — 3 fine phases per K-tile, each
// {ds_read subtile || 2x global_load_lds || s_barrier || lgkmcnt(0) ||
//  setprio(1) 16-MFMA cluster setprio(0) || s_barrier}; ONE counted
// vmcnt(6) per K-tile (depth-2, never 0 in steady state); no sched pins.
// ---------------------------------------------------------------------------
__global__ __launch_bounds__(512, 2)
void conv_fg8(const u16* __restrict__ xhi, const u16* __restrict__ xlo,
              u16* __restrict__ fhi, u16* __restrict__ flo,
              u16* __restrict__ gThi, u16* __restrict__ gTlo)
{
  __shared__ u16 lds[73728];                    // 144 KB
  const int bid = blockIdx.x;
  const int xcd = bid & 7, idx = bid >> 3;      // 2048 = 8 XCD x (64 tn x 4 tm)
  const int tn = xcd * 64 + (idx >> 2);
  const int tm = idx & 3;
  const bool gmode = tm >= 2;
  const int t = threadIdx.x, lane = t & 63, wid = t >> 6;
  const int wr = wid >> 1, wc = wid & 1;
  const int lr = lane & 15, lq = lane >> 4;

  // staging mapping: row = t>>2 (0..127), swizzled k-slot (involution)
  const int arow = t >> 2;
  const int kslot8 = (((t & 3) ^ ((t >> 3) & 3)) << 3);
  const int garA0 = tm * 256 + arow;
  const int garA1 = garA0 + 128;
  const int bxr = gmode ? ((((tn & 1) << 7) + arow) * 256 + (tn >> 1))
                        : (tn * 128 + arow);
  const int wbyte = wid * 1024;
  char* const L = (char*)lds;

  // fragment read offsets (u16 units), loop-invariant, matching read swizzle
  int offA[4], offB[4];
#pragma unroll
  for (int mi = 0; mi < 4; ++mi) {
    const int rowA = wr * 64 + mi * 16 + lr;
    offA[mi] = rowA * 32 + ((lq ^ ((rowA >> 1) & 3)) << 3);
  }
#pragma unroll
  for (int ni = 0; ni < 4; ++ni) {
    const int rowB = wc * 64 + ni * 16 + lr;
    offB[ni] = 16384 + rowB * 32 + ((lq ^ ((rowB >> 1) & 3)) << 3);
  }

  f32x4 acc[4][4] = {};

  // prologue: stage tiles 0 and 1 (12 gloads/thread), wait first tile's 6
#pragma unroll
  for (int Tp = 0; Tp < 2; ++Tp) {
    const int ko = Tp * 32 + kslot8;
    const int bb = Tp * 49152;
    gload16(Wsplit + (size_t)garA0 * 512 + ko,          L + bb + 0     + wbyte);
    gload16(Wsplit + (size_t)garA1 * 512 + ko,          L + bb + 8192  + wbyte);
    gload16(Wsplit + 524288 + (size_t)garA0 * 512 + ko, L + bb + 16384 + wbyte);
    gload16(Wsplit + 524288 + (size_t)garA1 * 512 + ko, L + bb + 24576 + wbyte);
    gload16(xhi + (size_t)bxr * 512 + ko,               L + bb + 32768 + wbyte);
    gload16(xlo + (size_t)bxr * 512 + ko,               L + bb + 40960 + wbyte);
  }
  asm volatile("s_waitcnt vmcnt(6)" ::: "memory");
  __builtin_amdgcn_s_barrier();

#pragma unroll 1
  for (int T = 0; T < 16; ++T) {
    const u16* Bp = lds + (T % 3) * 24576;
    const bool pf = (T + 2) < 16;
    const int bpo = ((T + 2) % 3) * 49152;
    const int ko = (T + 2) * 32 + kslot8;

    // ======== phase 0: read ah+bh, gload A-hi pair, MFMA hh ========
    short8 ah[4], bh[4];
#pragma unroll
    for (int mi = 0; mi < 4; ++mi) ah[mi] = *(const short8*)(Bp + offA[mi]);
#pragma unroll
    for (int ni = 0; ni < 4; ++ni) bh[ni] = *(const short8*)(Bp + offB[ni]);
    if (pf) {
      gload16(Wsplit + (size_t)garA0 * 512 + ko, L + bpo + 0    + wbyte);
      gload16(Wsplit + (size_t)garA1 * 512 + ko, L + bpo + 8192 + wbyte);
    }
    __builtin_amdgcn_s_barrier();
    asm volatile("s_waitcnt lgkmcnt(0)" ::: "memory");
    __builtin_amdgcn_s_setprio(1);
#pragma unroll
    for (int mi = 0; mi < 4; ++mi)
#pragma unroll
      for (int ni = 0; ni < 4; ++ni)
        acc[mi][ni] = MFMA16(ah[mi], bh[ni], acc[mi][ni], 0, 0, 0);
    __builtin_amdgcn_s_setprio(0);
    __builtin_amdgcn_s_barrier();

    // ======== phase 1: read bl, gload A-lo pair, MFMA hl ========
    short8 bl[4];
#pragma unroll
    for (int ni = 0; ni < 4; ++ni) bl[ni] = *(const short8*)(Bp + 4096 + offB[ni]);
    if (pf) {
      gload16(Wsplit + 524288 + (size_t)garA0 * 512 + ko, L + bpo + 16384 + wbyte);
      gload16(Wsplit + 524288 + (size_t)garA1 * 512 + ko, L + bpo + 24576 + wbyte);
    }
    __builtin_amdgcn_s_barrier();
    asm volatile("s_waitcnt lgkmcnt(0)" ::: "memory");
    __builtin_amdgcn_s_setprio(1);
#pragma unroll
    for (int mi = 0; mi < 4; ++mi)
#pragma unroll
      for (int ni = 0; ni < 4; ++ni)
        acc[mi][ni] = MFMA16(ah[mi], bl[ni], acc[mi][ni], 0, 0, 0);
    __builtin_amdgcn_s_setprio(0);
    __builtin_amdgcn_s_barrier();

    // ======== phase 2: read al, gload B pair, MFMA lh, counted vmcnt ========
    short8 al[4];
#pragma unroll
    for (int mi = 0; mi < 4; ++mi) al[mi] = *(const short8*)(Bp + 8192 + offA[mi]);
    if (pf) {
      gload16(xhi + (size_t)bxr * 512 + ko, L + bpo + 32768 + wbyte);
      gload16(xlo + (size_t)bxr * 512 + ko, L + bpo + 40960 + wbyte);
    }
    __builtin_amdgcn_s_barrier();
    asm volatile("s_waitcnt lgkmcnt(0)" ::: "memory");
    __builtin_amdgcn_s_setprio(1);
#pragma unroll
    for (int mi = 0; mi < 4; ++mi)
#pragma unroll
      for (int ni = 0; ni < 4; ++ni)
        acc[mi][ni] = MFMA16(al[mi], bh[ni], acc[mi][ni], 0, 0, 0);
    __builtin_amdgcn_s_setprio(0);
    // tile-end: T+1's 6 loads (issued during T-1) must be done; T+2's 6
    // (issued this tile) stay in flight — never drain to 0 until the tail.
    if (T < 14) { asm volatile("s_waitcnt vmcnt(6)" ::: "memory"); }
    else        { asm volatile("s_waitcnt vmcnt(0)" ::: "memory"); }
    __builtin_amdgcn_s_barrier();
  }

  // ---- epilogue: per-wave 64x64, hi/lo split write
  const int mbase = tm * 256 + wr * 64;
  const int cbase = tn * 128 + wc * 64;
  u16* dsthi = gmode ? gThi : fhi;
  u16* dstlo = gmode ? gTlo : flo;
  const int chb = gmode ? (mbase - 512) : mbase;
#pragma unroll
  for (int mi = 0; mi < 4; ++mi)
#pragma unroll
    for (int ni = 0; ni < 4; ++ni) {
      const int r0 = chb + mi * 16 + lq * 4;
      const int cc = cbase + ni * 16 + lr;
#pragma unroll
      for (int r = 0; r < 4; ++r) {
        float val = acc[mi][ni][r];
        u32 u = __float_as_uint(val);
        const size_t o = (size_t)(r0 + r) * 65536 + cc;
        dsthi[o] = (u16)(u >> 16);
        dstlo[o] = f2bf(val - __uint_as_float(u & 0xFFFF0000u));
      }
    }
}

// ---------------------------------------------------------------------------
// conv_h: plain bf16 GEMM h = rne(Wh) @ x, all-gload staging, out bf16.
// ---------------------------------------------------------------------------
__global__ __launch_bounds__(256)
void conv_h(const u16* __restrict__ xhi, u16* __restrict__ hb)
{
  __shared__ u16 sA[128 * 32], sB[128 * 32];
  const int bid = blockIdx.x;
  const int xcd = bid & 7, idx = bid >> 3;      // 2048 = 8 x (64 tn x 4 tm)
  const int tn = xcd * 64 + (idx >> 2);
  const int tm = idx & 3;
  const int t = threadIdx.x, lane = t & 63, wid = t >> 6;
  const int wr = wid >> 1, wc = wid & 1, lr = lane & 15, lq = lane >> 4;
  const int grl = t >> 2, gko = t & 3;
  const int ldsb = wid * 1024;

  f32x4 acc[4][4] = {};

  for (int k0 = 0; k0 < 512; k0 += 32) {
#pragma unroll
    for (int q = 0; q < 2; ++q) {
      const int row = q * 64 + grl;
      const size_t ao = (size_t)1048576 + (size_t)(tm * 128 + row) * 512 + k0 + gko * 8;
      gload16(Wsplit + ao, (char*)sA + q * 4096 + ldsb);
      const size_t bo = (size_t)(tn * 128 + row) * 512 + k0 + gko * 8;
      gload16(xhi + bo, (char*)sB + q * 4096 + ldsb);
    }
    __syncthreads();
    short8 af[4], bfr[4];
#pragma unroll
    for (int mi = 0; mi < 4; ++mi)
      af[mi] = *(const short8*)(sA + (wr * 64 + mi * 16 + lr) * 32 + lq * 8);
#pragma unroll
    for (int ni = 0; ni < 4; ++ni)
      bfr[ni] = *(const short8*)(sB + (wc * 64 + ni * 16 + lr) * 32 + lq * 8);
#pragma unroll
    for (int mi = 0; mi < 4; ++mi)
#pragma unroll
      for (int ni = 0; ni < 4; ++ni)
        acc[mi][ni] = MFMA16(af[mi], bfr[ni], acc[mi][ni], 0, 0, 0);
    __syncthreads();
  }
  const int rb = tm * 128 + wr * 64, cbase = tn * 128 + wc * 64;
#pragma unroll
  for (int mi = 0; mi < 4; ++mi)
#pragma unroll
    for (int ni = 0; ni < 4; ++ni) {
      const int r0 = rb + mi * 16 + lq * 4, cc = cbase + ni * 16 + lr;
#pragma unroll
      for (int r = 0; r < 4; ++r)
        hb[(size_t)(r0 + r) * 65536 + cc] = f2bf(acc[mi][ni][r]);
    }
}

// ---------------------------------------------------------------------------
// scores256: one block per channel. S = f[c] @ gT[c]^T (EMU), 256x256 tile,
// full-column softmax -> normalized PT[c][j][i] bf16.
// ---------------------------------------------------------------------------
__global__ __launch_bounds__(512, 2)
void scores256(const u16* __restrict__ fhi, const u16* __restrict__ flo,
               const u16* __restrict__ gThi, const u16* __restrict__ gTlo,
               u16* __restrict__ Pt)
{
  __shared__ u16 sAh[256 * 32], sAl[256 * 32], sBh[256 * 32], sBl[256 * 32]; // 4x16 KB
  float* cmax = (float*)sAh;          // aliases staging (dead after K-loop)
  float* csum = (float*)(sAh + 2048);
  const int c = blockIdx.x;
  const size_t cb = (size_t)c * 65536;
  const int t = threadIdx.x, lane = t & 63, wid = t >> 6;
  const int wr = wid >> 2, wc = wid & 3, lr = lane & 15, lq = lane >> 4;
  const int grl = t >> 2, gko = t & 3;
  const int ldsb = wid * 1024;

  f32x4 acc[8][4] = {};

  for (int k0 = 0; k0 < 256; k0 += 32) {
#pragma unroll
    for (int q = 0; q < 2; ++q) {
      const size_t ao = cb + (size_t)(q * 128 + grl) * 256 + k0 + gko * 8;
      gload16(fhi + ao,  (char*)sAh + q * 8192 + ldsb);
      gload16(flo + ao,  (char*)sAl + q * 8192 + ldsb);
      gload16(gThi + ao, (char*)sBh + q * 8192 + ldsb);
      gload16(gTlo + ao, (char*)sBl + q * 8192 + ldsb);
    }
    __syncthreads();
    short8 bh[4], bl[4];
#pragma unroll
    for (int ni = 0; ni < 4; ++ni) {
      bh[ni] = *(const short8*)(sBh + (wc * 64 + ni * 16 + lr) * 32 + lq * 8);
      bl[ni] = *(const short8*)(sBl + (wc * 64 + ni * 16 + lr) * 32 + lq * 8);
    }
#pragma unroll
    for (int mi = 0; mi < 8; ++mi) {
      short8 ah = *(const short8*)(sAh + (wr * 128 + mi * 16 + lr) * 32 + lq * 8);
      short8 al = *(const short8*)(sAl + (wr * 128 + mi * 16 + lr) * 32 + lq * 8);
#pragma unroll
      for (int ni = 0; ni < 4; ++ni) {
        acc[mi][ni] = MFMA16(ah, bh[ni], acc[mi][ni], 0, 0, 0);
        acc[mi][ni] = MFMA16(ah, bl[ni], acc[mi][ni], 0, 0, 0);
        acc[mi][ni] = MFMA16(al, bh[ni], acc[mi][ni], 0, 0, 0);
      }
    }
    __syncthreads();
  }

#pragma unroll
  for (int ni = 0; ni < 4; ++ni) {
    const int j = wc * 64 + ni * 16 + lr;
    float m = -3.4e38f;
#pragma unroll
    for (int mi = 0; mi < 8; ++mi) {
      f32x4 a = acc[mi][ni];
      m = fmaxf(m, fmaxf(fmaxf(a[0], a[1]), fmaxf(a[2], a[3])));
    }
    m = fmaxf(m, __shfl_xor(m, 16));
    m = fmaxf(m, __shfl_xor(m, 32));
    cmax[wr * 256 + j] = m;
  }
  __syncthreads();
#pragma unroll
  for (int ni = 0; ni < 4; ++ni) {
    const int j = wc * 64 + ni * 16 + lr;
    const float M = fmaxf(cmax[j], cmax[256 + j]);
    float s = 0.f;
#pragma unroll
    for (int mi = 0; mi < 8; ++mi)
#pragma unroll
      for (int r = 0; r < 4; ++r) {
        float e = __expf(acc[mi][ni][r] - M);
        acc[mi][ni][r] = e; s += e;
      }
    s += __shfl_xor(s, 16);
    s += __shfl_xor(s, 32);
    csum[wr * 256 + j] = s;
  }
  __syncthreads();
#pragma unroll
  for (int ni = 0; ni < 4; ++ni) {
    const int j = wc * 64 + ni * 16 + lr;
    const float rs = 1.f / (csum[j] + csum[256 + j]);
#pragma unroll
    for (int mi = 0; mi < 8; ++mi) {
      u32 w0 = cvtpk(acc[mi][ni][0] * rs, acc[mi][ni][1] * rs);
      u32 w1 = cvtpk(acc[mi][ni][2] * rs, acc[mi][ni][3] * rs);
      *(u32x2*)(Pt + cb + (size_t)j * 256 + wr * 128 + mi * 16 + lq * 4) = (u32x2){w0, w1};
    }
  }
}

// ---------------------------------------------------------------------------
// attn: out[c,i,j] = x[c,i,j] + sum_k h[c,i,k] * PT[c,j,k]. Plain bf16.
// ---------------------------------------------------------------------------
__global__ __launch_bounds__(256)
void attn_kernel(const u16* __restrict__ hb, const u16* __restrict__ Pt,
                 const float* __restrict__ x, float* __restrict__ out)
{
  __shared__ u16 sA[128 * 32], sB[128 * 32];
  const int bid = blockIdx.x;
  const int wg = (bid & 7) * 256 + (bid >> 3);
  const int c = wg >> 2, tm = (wg >> 1) & 1, tn = wg & 1;
  const int t = threadIdx.x, lane = t & 63, wid = t >> 6;
  const int wr = wid >> 1, wc = wid & 1, lr = lane & 15, lq = lane >> 4;
  const size_t cb = (size_t)c * 65536;
  const int grl = t >> 2, gko = t & 3;
  const int ldsb = wid * 1024;

  f32x4 acc[4][4] = {};

  for (int k0 = 0; k0 < 256; k0 += 32) {
#pragma unroll
    for (int q = 0; q < 2; ++q) {
      const int row = q * 64 + grl;
      gload16(hb + cb + (size_t)(tm * 128 + row) * 256 + k0 + gko * 8,
              (char*)sA + q * 4096 + ldsb);
      gload16(Pt + cb + (size_t)(tn * 128 + row) * 256 + k0 + gko * 8,
              (char*)sB + q * 4096 + ldsb);
    }
    __syncthreads();
    short8 af[4], bfr[4];
#pragma unroll
    for (int mi = 0; mi < 4; ++mi)
      af[mi] = *(const short8*)(sA + (wr * 64 + mi * 16 + lr) * 32 + lq * 8);
#pragma unroll
    for (int ni = 0; ni < 4; ++ni)
      bfr[ni] = *(const short8*)(sB + (wc * 64 + ni * 16 + lr) * 32 + lq * 8);
#pragma unroll
    for (int mi = 0; mi < 4; ++mi)
#pragma unroll
      for (int ni = 0; ni < 4; ++ni)
        acc[mi][ni] = MFMA16(af[mi], bfr[ni], acc[mi][ni], 0, 0, 0);
    __syncthreads();
  }

  const float* Xc = x + cb;
  float* Oc = out + cb;
  const int rb = tm * 128 + wr * 64, cbase = tn * 128 + wc * 64;
#pragma unroll
  for (int mi = 0; mi < 4; ++mi)
#pragma unroll
    for (int ni = 0; ni < 4; ++ni) {
      const int r0 = rb + mi * 16 + lq * 4, cc = cbase + ni * 16 + lr;
#pragma unroll
      for (int r = 0; r < 4; ++r) {
        const size_t idx = (size_t)(r0 + r) * 256 + cc;
        Oc[idx] = Xc[idx] + acc[mi][ni][r];
      }
    }
}

// ---------------------------------------------------------------------------
extern "C" void kernel_launch(void* const* d_in, const int* in_sizes, int n_in,
                              void* d_out, int out_size, void* d_ws, size_t ws_size,
                              hipStream_t stream)
{
  (void)in_sizes; (void)n_in; (void)out_size; (void)ws_size;
  const float* x  = (const float*)d_in[0];
  const float* Wf = (const float*)d_in[1];
  const float* Wg = (const float*)d_in[2];
  const float* Wh = (const float*)d_in[3];
  float* out = (float*)d_out;
  char*  ws  = (char*)d_ws;

  // ws (256 MiB): [xhi 64][xlo 64][gThi 64][gTlo 64]; d_out hosts f hi/lo.
  u16* xhi  = (u16*)ws;
  u16* xlo  = (u16*)(ws + 67108864);
  u16* gThi = (u16*)(ws + 134217728);
  u16* gTlo = (u16*)(ws + 201326592);
  u16* fhi  = (u16*)d_out;
  u16* flo  = (u16*)d_out + 33554432;
  u16* hb   = xlo;   // h overwrites xlo after conv_fg8
  u16* Pt   = xhi;   // PT overwrites xhi after conv_h

  dim3 blk(256, 1, 1);
  prep_w     <<<dim3(1536, 1, 1), blk, 0, stream>>>(Wf, Wg, Wh);
  prep_x     <<<dim3(2048, 1, 1), blk, 0, stream>>>(x, xhi, xlo);
  conv_fg8   <<<dim3(2048, 1, 1), dim3(512, 1, 1), 0, stream>>>(xhi, xlo, fhi, flo, gThi, gTlo);
  conv_h     <<<dim3(2048, 1, 1), blk, 0, stream>>>(xhi, hb);
  scores256  <<<dim3(512, 1, 1), dim3(512, 1, 1), 0, stream>>>(fhi, flo, gThi, gTlo, Pt);
  attn_kernel<<<dim3(2048, 1, 1), blk, 0, stream>>>(hb, Pt, x, out);
}